// Round 5
// baseline (383.683 us; speedup 1.0000x reference)
//
#include <hip/hip_runtime.h>
#include <stdint.h>

#define NROWS 16384
#define QNUM  8192
#define ED    512
#define BM    128
#define BN    128
#define KTILES 8           // K tiles of 64 elements
#define QBLKS  (QNUM / BN) // 64
#define DELTA  0.02f       // >=6 sigma of (err_i - err_j) for fp8 ranking noise
#define ESLOT  33          // 32 top2-key entries per row + 1 pad (uint2 units)

typedef int   i32x8  __attribute__((ext_vector_type(8)));   // 32 B fp8 fragment (8 VGPR)
typedef float f32x16 __attribute__((ext_vector_type(16)));  // 32x32 MFMA accumulator

// sortable key: monotone float->uint, low 13 bits replaced by q index (0..8191).
// score perturbation from clearing 13 mantissa bits <= ~6e-5 at |s|~0.1 — absorbed
// by DELTA. min-key == (min score, tie -> min idx).
static __device__ __forceinline__ unsigned enc_key(float s, unsigned idx) {
    const unsigned b = __float_as_uint(s);
    const unsigned m = (unsigned)(((int)b) >> 31) | 0x80000000u;
    return ((b ^ m) & 0xFFFFE000u) | idx;
}
// decode key -> floored float value (<= true score)
static __device__ __forceinline__ float dec_key(unsigned k) {
    const unsigned u = k & 0xFFFFE000u;
    return (u & 0x80000000u) ? __uint_as_float(u ^ 0x80000000u)
                             : __uint_as_float(~u);
}

static __device__ __forceinline__ void ins3k(unsigned& v1, unsigned& v2, unsigned& v3,
                                             unsigned k) {
    const bool b1 = k < v1, b2 = k < v2, b3 = k < v3;
    v3 = b2 ? v2 : (b3 ? k : v3);
    v2 = b1 ? v1 : (b2 ? k : v2);
    v1 = b1 ? k : v1;
}

// ---------------- fused prep: numpy-pairwise sumsq + fp32->fp8 MX-granule layout ----------------
// Sumsq phase is the R2-verified numpy-pairwise tree, verbatim. fp8 phase emits the
// 32x32x64 f8f6f4 fragment layout: 32-row tiles (rt), 64-elem k-tiles (kt); lane
// l = kb*32 + rr holds row rr's bytes k = kt*64 + kb*32 .. +32, stored contiguously
// as one 32 B block at index G = (rt*8 + kt)*64 + kb*32 + rr.
#define SROWS 32
#define SSTRIDE 520
__global__ __launch_bounds__(256) void k_prep_sumsq(const float* __restrict__ src,
                                                    float* __restrict__ dst_sq,
                                                    unsigned long long* __restrict__ dst8,
                                                    float scale) {
    __shared__ float ld[SROWS * SSTRIDE];
    const int t = threadIdx.x;
    const size_t base = (size_t)blockIdx.x * SROWS * ED;
    #pragma unroll
    for (int k = 0; k < 16; ++k) {
        int u = k * 256 + t;
        int row = u >> 7;
        int c4  = u & 127;
        float4 v = ((const float4*)(src + base))[u];
        float* d = ld + row * SSTRIDE + c4 * 4;
        d[0] = v.x; d[1] = v.y; d[2] = v.z; d[3] = v.w;
    }
    __syncthreads();
    const int row = t >> 3, j = t & 7;
    const float* a = ld + row * SSTRIDE;
    float B[4];
    #pragma unroll
    for (int b = 0; b < 4; ++b) {
        const float* p = a + b * 128 + j;
        float r = __fmul_rn(p[0], p[0]);
        #pragma unroll
        for (int i = 1; i < 16; ++i) {
            float q = p[8 * i];
            r = __fadd_rn(r, __fmul_rn(q, q));
        }
        float t1 = __fadd_rn(r,  __shfl_xor(r,  1, 64));
        float t2 = __fadd_rn(t1, __shfl_xor(t1, 2, 64));
        B[b]     = __fadd_rn(t2, __shfl_xor(t2, 4, 64));
    }
    if (j == 0)
        dst_sq[(size_t)blockIdx.x * SROWS + row] =
            __fadd_rn(__fadd_rn(B[0], B[1]), __fadd_rn(B[2], B[3]));

    // fp8 phase: thread (row, j) owns k-tile kt = j (64 elems = two 32 B blocks)
    #pragma unroll
    for (int kb = 0; kb < 2; ++kb) {
        const float* e = a + j * 64 + kb * 32;
        unsigned d[8];
        #pragma unroll
        for (int p = 0; p < 8; ++p) {
            int w0 = __builtin_amdgcn_cvt_pk_fp8_f32(e[4*p+0] * scale, e[4*p+1] * scale, 0,  false);
            w0     = __builtin_amdgcn_cvt_pk_fp8_f32(e[4*p+2] * scale, e[4*p+3] * scale, w0, true);
            d[p] = (unsigned)w0;
        }
        const size_t G = ((size_t)(blockIdx.x * 8 + j) * 64 + kb * 32 + row);
        uint4* dp = (uint4*)dst8 + G * 2;
        dp[0] = make_uint4(d[0], d[1], d[2], d[3]);
        dp[1] = make_uint4(d[4], d[5], d[6], d[7]);
    }
}

// ---------------- phase 1: MX-scaled fp8 MFMA (unit scales) + sortable-key top-2 epilogue ----------------
// 32x32x64 f8f6f4 with e8m0 scale 0x7F (=1.0): dot products numerically identical to
// the verified 16x16x32 fp8 path, at 2.14x the MFMA rate.
// R5: 8 waves x (64x32 output) per 128x128 block. R2/R4 proved the MX MFMA floor
// (28.7 us) is reached but 2 waves/SIMD can't hide load/VALU gaps (47% issue util).
// Per-wave acc 64->32 regs, single-buffered frags 24 regs -> live set ~95 under the
// 128-reg occupancy step (m69) -> 4 waves/SIMD, R1-style cross-wave overlap.
// Epilogue: top-2 per 4-col group (32 slots/row) — superset of the verified
// 2-per-16-col candidate info, so DELTA/rescore correctness carries over.
// C/D layout (HW-verified, shape-determined): col = lane&31,
// row = (reg&3) + 8*(reg>>2) + 4*(lane>>5).
__global__ __launch_bounds__(512, 4) void k_gemm_top2(
        const uint4* __restrict__ xb,   // MX-granule fp8 (32 B per lane-block)
        const uint4* __restrict__ wb,   // MX-granule fp8 (x512)
        const float* __restrict__ wsqf,
        uint4* __restrict__ p3) {
    __shared__ uint2 ered[BM * ESLOT];   // 33,792 B

    const int t  = threadIdx.x;
    const int wv = t >> 6;   // 0..7
    const int l  = t & 63;
    const int h  = l >> 5;   // lane half -> row +4
    const int cn = l & 31;   // MFMA col within 32-col tile
    const int RB = (wv >> 2) * 64;   // row base: waves 0-3 -> 0, 4-7 -> 64
    const int CB = (wv & 3) * 32;    // col base: 4 col-waves x 32

    // XCD-aware swizzle (R6+): id%8 = XCD; each XCD keeps 8 q-panels L2-hot.
    const int id = blockIdx.x;
    const int qb = (id & 7) * 8 + ((id >> 3) & 7);  // 0..63
    const int rb = id >> 6;                          // 0..127
    const int q0 = qb * BN;
    const int r0 = rb * BM;

    f32x16 acc[2];
    #pragma unroll
    for (int i = 0; i < 2; ++i)
        #pragma unroll
        for (int r = 0; r < 16; ++r)
            acc[i][r] = 0.f;

    const int rt0 = (r0 + RB) >> 5;   // two consecutive 32-row A tiles
    const int qt  = (q0 + CB) >> 5;   // one 32-col B tile
    const uint4* ga = xb + ((size_t)(rt0 * 8) * 64 + l) * 2;
    const uint4* gb = wb + ((size_t)(qt  * 8) * 64 + l) * 2;

    i32x8 Af[2], Bf;   // single-buffered: TLP (4 waves/SIMD) hides latency (m114)

#define LD32(dst, p, blk) do {                                   \
        const uint4 u0 = (p)[(size_t)(blk) * 128];               \
        const uint4 u1 = (p)[(size_t)(blk) * 128 + 1];           \
        dst = (i32x8){(int)u0.x, (int)u0.y, (int)u0.z, (int)u0.w,\
                      (int)u1.x, (int)u1.y, (int)u1.z, (int)u1.w};\
    } while (0)

    #pragma unroll
    for (int kt = 0; kt < KTILES; ++kt) {
        LD32(Af[0], ga, kt);
        LD32(Af[1], ga, 8 + kt);
        LD32(Bf,    gb, kt);
        __builtin_amdgcn_s_setprio(1);
        #pragma unroll
        for (int i = 0; i < 2; ++i)
            acc[i] = __builtin_amdgcn_mfma_scale_f32_32x32x64_f8f6f4(
                    Af[i], Bf, acc[i],
                    0, 0,                       // cbsz = fp8, blgp = fp8
                    0, 0x7F7F7F7F,              // scale A: e8m0 1.0
                    0, 0x7F7F7F7F);             // scale B: e8m0 1.0
        __builtin_amdgcn_s_setprio(0);
    }

    // epilogue: score = wsq - 2*dot*2^-9 (w scaled by 2^9 at prep)
    const int qj = q0 + CB + cn;
    const float    wsqv = wsqf[qj];
    const unsigned kidx = (unsigned)qj;

    #pragma unroll
    for (int i = 0; i < 2; ++i) {
        #pragma unroll
        for (int rg = 0; rg < 4; ++rg) {
            #pragma unroll
            for (int rr = 0; rr < 4; ++rr) {
                const int reg = rg * 4 + rr;
                const unsigned k0 = enc_key(fmaf(-0.00390625f, acc[i][reg], wsqv), kidx);
                // xor-8: top2 of col pair {cn, cn^8}
                const unsigned o0 = __shfl_xor((int)k0, 8, 64);
                unsigned v1 = min(k0, o0);
                unsigned v2 = max(k0, o0);
                // xor-16: top2 of 4-col group {cn, cn^8, cn^16, cn^24}
                {
                    const unsigned o1 = __shfl_xor((int)v1, 16, 64);
                    const unsigned o2 = __shfl_xor((int)v2, 16, 64);
                    const unsigned nv1 = min(v1, o1);
                    v2 = min(max(v1, o1), min(v2, o2));
                    v1 = nv1;
                }
                if ((l & 24) == 0) {   // one representative per 4-lane col-group, per half
                    const int row = RB + i * 32 + rr + 8 * rg + 4 * h;
                    ered[row * ESLOT + (wv & 3) * 8 + (l & 7)] = make_uint2(v1, v2);
                }
            }
        }
    }
    __syncthreads();
    if (t < BM) {
        const uint2* e = &ered[t * ESLOT];
        unsigned v1 = 0xFFFFFFFFu, v2 = 0xFFFFFFFFu, v3 = 0xFFFFFFFFu;
        #pragma unroll
        for (int k = 0; k < 32; ++k) {
            const uint2 E = e[k];
            ins3k(v1, v2, v3, E.x);
            ins3k(v1, v2, v3, E.y);
        }
        p3[(size_t)(r0 + t) * QBLKS + qb] = make_uint4(v1, v2, v3, 0xFFFFFFFFu);
    }
}

// ---------------- phase 2: fp32-emulated (numpy semantics) rescore + gather ----------------
__global__ __launch_bounds__(256) void k_rescore(
        const uint4* __restrict__ p3,
        const float* __restrict__ x,
        const float* __restrict__ wt,
        const float* __restrict__ wsqf,
        const float* __restrict__ xsqf,
        float* __restrict__ outq,
        float* __restrict__ outi) {
    const int wv = threadIdx.x >> 6, l = threadIdx.x & 63;
    const int row = blockIdx.x * 4 + wv;

    const uint4 P = p3[(size_t)row * QBLKS + l];
    unsigned vk[3] = { P.x, P.y, P.z };

    unsigned gk = vk[0];
    #pragma unroll
    for (int m = 1; m < 64; m <<= 1) gk = min(gk, (unsigned)__shfl_xor((int)gk, m, 64));
    // threshold in key space: decode floored gm, add DELTA, re-encode, idx bits = 1s
    const float tf = dec_key(gk) + DELTA;
    const unsigned tb = __float_as_uint(tf);
    const unsigned tm = (unsigned)(((int)tb) >> 31) | 0x80000000u;
    const unsigned thrkey = (tb ^ tm) | 0x1FFFu;

    const float4* xp = (const float4*)(x + (size_t)row * ED + l * 8);
    const float4 xa = xp[0], xbv = xp[1];
    const float xsq = xsqf[row];

    float bestv = 3.4e38f; int bestq = 0x7fffffff;
    #pragma unroll
    for (int k = 0; k < 3; ++k) {
        unsigned long long mm = __ballot(vk[k] <= thrkey);
        while (mm) {
            const int ln = __ffsll(mm) - 1;
            mm &= mm - 1;
            const int q = __shfl((int)vk[k], ln, 64) & 0x1FFF;
            const float4* wp = (const float4*)(wt + (size_t)q * ED + l * 8);
            const float4 wa = wp[0], wbv = wp[1];
            double d = (double)xa.x * wa.x + (double)xa.y * wa.y
                     + (double)xa.z * wa.z + (double)xa.w * wa.w
                     + (double)xbv.x * wbv.x + (double)xbv.y * wbv.y
                     + (double)xbv.z * wbv.z + (double)xbv.w * wbv.w;
            #pragma unroll
            for (int m = 1; m < 64; m <<= 1) d += __shfl_xor(d, m, 64);
            // numpy fp32 semantics: fl32( fl32(x_sq - 2*dot) + w_sq ), first-occurrence argmin
            const float dotf = (float)d;
            const float t1 = __fadd_rn(xsq, __fmul_rn(-2.0f, dotf));
            const float sc = __fadd_rn(t1, wsqf[q]);
            if (sc < bestv || (sc == bestv && q < bestq)) { bestv = sc; bestq = q; }
        }
    }
    const float4* wp = (const float4*)(wt + (size_t)bestq * ED + l * 8);
    float4* op = (float4*)(outq + (size_t)row * ED + l * 8);
    op[0] = wp[0]; op[1] = wp[1];
    if (l == 0) outi[row] = (float)bestq;
}

extern "C" void kernel_launch(void* const* d_in, const int* in_sizes, int n_in,
                              void* d_out, int out_size, void* d_ws, size_t ws_size,
                              hipStream_t stream) {
    (void)in_sizes; (void)n_in; (void)out_size; (void)ws_size;
    const float* x  = (const float*)d_in[0];
    const float* wt = (const float*)d_in[1];

    char* ws = (char*)d_ws;
    unsigned long long* xb8 = (unsigned long long*)ws;               //  8,388,608 B
    unsigned long long* wb8 = (unsigned long long*)(ws + 8388608);   //  4,194,304 B
    float* wsqf = (float*)(ws + 12582912);                           //     32,768 B
    float* xsqf = (float*)(ws + 12615680);                           //     65,536 B
    uint4* p3   = (uint4*)(ws + 12681216);                           // 16,777,216 B (end ~29.5 MB)

    float* outq = (float*)d_out;
    float* outi = outq + (size_t)NROWS * ED;

    k_prep_sumsq<<<NROWS / SROWS, 256, 0, stream>>>(x,  xsqf, xb8, 1.0f);
    k_prep_sumsq<<<QNUM  / SROWS, 256, 0, stream>>>(wt, wsqf, wb8, 512.0f);  // 2^9 lifts w out of e4m3 subnormals
    k_gemm_top2<<<8192, 512, 0, stream>>>((const uint4*)xb8, (const uint4*)wb8, wsqf, p3);
    k_rescore<<<4096, 256, 0, stream>>>(p3, x, wt, wsqf, xsqf, outq, outi);
}

// Round 6
// 350.890 us; speedup vs baseline: 1.0935x; 1.0935x over previous
//
#include <hip/hip_runtime.h>
#include <stdint.h>

#define NROWS 16384
#define QNUM  8192
#define ED    512
#define BM    128
#define BN    128
#define KTILES 8           // K tiles of 64 elements
#define QBLKS  (QNUM / BN) // 64
#define DELTA  0.02f       // >=6 sigma of (err_i - err_j) for fp8 ranking noise
#define ESLOT  33          // 32 top2-key entries per row + 1 pad (uint2 units)

typedef int   i32x8  __attribute__((ext_vector_type(8)));   // 32 B fp8 fragment (8 VGPR)
typedef float f32x16 __attribute__((ext_vector_type(16)));  // 32x32 MFMA accumulator

// sortable key: monotone float->uint, low 13 bits replaced by q index (0..8191).
// score perturbation from clearing 13 mantissa bits <= ~6e-5 at |s|~0.1 — absorbed
// by DELTA. min-key == (min score, tie -> min idx).
static __device__ __forceinline__ unsigned enc_key(float s, unsigned idx) {
    const unsigned b = __float_as_uint(s);
    const unsigned m = (unsigned)(((int)b) >> 31) | 0x80000000u;
    return ((b ^ m) & 0xFFFFE000u) | idx;
}
// decode key -> floored float value (<= true score)
static __device__ __forceinline__ float dec_key(unsigned k) {
    const unsigned u = k & 0xFFFFE000u;
    return (u & 0x80000000u) ? __uint_as_float(u ^ 0x80000000u)
                             : __uint_as_float(~u);
}

static __device__ __forceinline__ void ins3k(unsigned& v1, unsigned& v2, unsigned& v3,
                                             unsigned k) {
    const bool b1 = k < v1, b2 = k < v2, b3 = k < v3;
    v3 = b2 ? v2 : (b3 ? k : v3);
    v2 = b1 ? v1 : (b2 ? k : v2);
    v1 = b1 ? k : v1;
}

// ---------------- fused prep: numpy-pairwise sumsq + fp32->fp8 MX-granule layout ----------------
// Sumsq phase is the R2-verified numpy-pairwise tree, verbatim. fp8 phase emits the
// 32x32x64 f8f6f4 fragment layout: 32-row tiles (rt), 64-elem k-tiles (kt); lane
// l = kb*32 + rr holds row rr's bytes k = kt*64 + kb*32 .. +32, stored contiguously
// as one 32 B block at index G = (rt*8 + kt)*64 + kb*32 + rr.
#define SROWS 32
#define SSTRIDE 520
__global__ __launch_bounds__(256) void k_prep_sumsq(const float* __restrict__ src,
                                                    float* __restrict__ dst_sq,
                                                    unsigned long long* __restrict__ dst8,
                                                    float scale) {
    __shared__ float ld[SROWS * SSTRIDE];
    const int t = threadIdx.x;
    const size_t base = (size_t)blockIdx.x * SROWS * ED;
    #pragma unroll
    for (int k = 0; k < 16; ++k) {
        int u = k * 256 + t;
        int row = u >> 7;
        int c4  = u & 127;
        float4 v = ((const float4*)(src + base))[u];
        float* d = ld + row * SSTRIDE + c4 * 4;
        d[0] = v.x; d[1] = v.y; d[2] = v.z; d[3] = v.w;
    }
    __syncthreads();
    const int row = t >> 3, j = t & 7;
    const float* a = ld + row * SSTRIDE;
    float B[4];
    #pragma unroll
    for (int b = 0; b < 4; ++b) {
        const float* p = a + b * 128 + j;
        float r = __fmul_rn(p[0], p[0]);
        #pragma unroll
        for (int i = 1; i < 16; ++i) {
            float q = p[8 * i];
            r = __fadd_rn(r, __fmul_rn(q, q));
        }
        float t1 = __fadd_rn(r,  __shfl_xor(r,  1, 64));
        float t2 = __fadd_rn(t1, __shfl_xor(t1, 2, 64));
        B[b]     = __fadd_rn(t2, __shfl_xor(t2, 4, 64));
    }
    if (j == 0)
        dst_sq[(size_t)blockIdx.x * SROWS + row] =
            __fadd_rn(__fadd_rn(B[0], B[1]), __fadd_rn(B[2], B[3]));

    // fp8 phase: thread (row, j) owns k-tile kt = j (64 elems = two 32 B blocks)
    #pragma unroll
    for (int kb = 0; kb < 2; ++kb) {
        const float* e = a + j * 64 + kb * 32;
        unsigned d[8];
        #pragma unroll
        for (int p = 0; p < 8; ++p) {
            int w0 = __builtin_amdgcn_cvt_pk_fp8_f32(e[4*p+0] * scale, e[4*p+1] * scale, 0,  false);
            w0     = __builtin_amdgcn_cvt_pk_fp8_f32(e[4*p+2] * scale, e[4*p+3] * scale, w0, true);
            d[p] = (unsigned)w0;
        }
        const size_t G = ((size_t)(blockIdx.x * 8 + j) * 64 + kb * 32 + row);
        uint4* dp = (uint4*)dst8 + G * 2;
        dp[0] = make_uint4(d[0], d[1], d[2], d[3]);
        dp[1] = make_uint4(d[4], d[5], d[6], d[7]);
    }
}

// ---------------- phase 1: MX-scaled fp8 MFMA (unit scales) + sortable-key top-2 epilogue ----------------
// 32x32x64 f8f6f4 with e8m0 scale 0x7F (=1.0): dot products numerically identical to
// the verified 16x16x32 fp8 path, at 2.14x the MFMA rate.
// R6: R5's 8-wave x (64x32) structure, but NO min-occupancy launch_bounds arg.
// Evidence: every round with a min-occupancy hint spilled (R3: (256,3) -> 803 MB
// scratch writes; R5: (512,4) -> 64-reg budget, 540 MB scratch). Every round
// without over-constraint was spill-free. Live set ~95 regs -> allocator lands
// ~100 -> 5 waves/SIMD naturally (512-reg pool, m69). TLP does the latency
// hiding (m114), as in R1's 90%-issue-util kernel.
// Epilogue: top-2 per 4-col group (32 slots/row) — superset of the verified
// 2-per-16-col candidate info; passed correctness in R5 even while spilling.
// C/D layout (HW-verified, shape-determined): col = lane&31,
// row = (reg&3) + 8*(reg>>2) + 4*(lane>>5).
__global__ __launch_bounds__(512) void k_gemm_top2(
        const uint4* __restrict__ xb,   // MX-granule fp8 (32 B per lane-block)
        const uint4* __restrict__ wb,   // MX-granule fp8 (x512)
        const float* __restrict__ wsqf,
        uint4* __restrict__ p3) {
    __shared__ uint2 ered[BM * ESLOT];   // 33,792 B

    const int t  = threadIdx.x;
    const int wv = t >> 6;   // 0..7
    const int l  = t & 63;
    const int h  = l >> 5;   // lane half -> row +4
    const int cn = l & 31;   // MFMA col within 32-col tile
    const int RB = (wv >> 2) * 64;   // row base: waves 0-3 -> 0, 4-7 -> 64
    const int CB = (wv & 3) * 32;    // col base: 4 col-waves x 32

    // XCD-aware swizzle (R6+): id%8 = XCD; each XCD keeps 8 q-panels L2-hot.
    const int id = blockIdx.x;
    const int qb = (id & 7) * 8 + ((id >> 3) & 7);  // 0..63
    const int rb = id >> 6;                          // 0..127
    const int q0 = qb * BN;
    const int r0 = rb * BM;

    f32x16 acc[2];
    #pragma unroll
    for (int i = 0; i < 2; ++i)
        #pragma unroll
        for (int r = 0; r < 16; ++r)
            acc[i][r] = 0.f;

    const int rt0 = (r0 + RB) >> 5;   // two consecutive 32-row A tiles
    const int qt  = (q0 + CB) >> 5;   // one 32-col B tile
    const uint4* ga = xb + ((size_t)(rt0 * 8) * 64 + l) * 2;
    const uint4* gb = wb + ((size_t)(qt  * 8) * 64 + l) * 2;

    i32x8 Af[2], Bf;   // single-buffered: TLP (4-5 waves/SIMD) hides latency (m114)

#define LD32(dst, p, blk) do {                                   \
        const uint4 u0 = (p)[(size_t)(blk) * 128];               \
        const uint4 u1 = (p)[(size_t)(blk) * 128 + 1];           \
        dst = (i32x8){(int)u0.x, (int)u0.y, (int)u0.z, (int)u0.w,\
                      (int)u1.x, (int)u1.y, (int)u1.z, (int)u1.w};\
    } while (0)

    #pragma unroll
    for (int kt = 0; kt < KTILES; ++kt) {
        LD32(Af[0], ga, kt);
        LD32(Af[1], ga, 8 + kt);
        LD32(Bf,    gb, kt);
        __builtin_amdgcn_s_setprio(1);
        #pragma unroll
        for (int i = 0; i < 2; ++i)
            acc[i] = __builtin_amdgcn_mfma_scale_f32_32x32x64_f8f6f4(
                    Af[i], Bf, acc[i],
                    0, 0,                       // cbsz = fp8, blgp = fp8
                    0, 0x7F7F7F7F,              // scale A: e8m0 1.0
                    0, 0x7F7F7F7F);             // scale B: e8m0 1.0
        __builtin_amdgcn_s_setprio(0);
    }

    // epilogue: score = wsq - 2*dot*2^-9 (w scaled by 2^9 at prep)
    const int qj = q0 + CB + cn;
    const float    wsqv = wsqf[qj];
    const unsigned kidx = (unsigned)qj;

    #pragma unroll
    for (int i = 0; i < 2; ++i) {
        #pragma unroll
        for (int rg = 0; rg < 4; ++rg) {
            #pragma unroll
            for (int rr = 0; rr < 4; ++rr) {
                const int reg = rg * 4 + rr;
                const unsigned k0 = enc_key(fmaf(-0.00390625f, acc[i][reg], wsqv), kidx);
                // xor-8: top2 of col pair {cn, cn^8}
                const unsigned o0 = __shfl_xor((int)k0, 8, 64);
                unsigned v1 = min(k0, o0);
                unsigned v2 = max(k0, o0);
                // xor-16: top2 of 4-col group {cn, cn^8, cn^16, cn^24}
                {
                    const unsigned o1 = __shfl_xor((int)v1, 16, 64);
                    const unsigned o2 = __shfl_xor((int)v2, 16, 64);
                    const unsigned nv1 = min(v1, o1);
                    v2 = min(max(v1, o1), min(v2, o2));
                    v1 = nv1;
                }
                if ((l & 24) == 0) {   // one representative per 4-lane col-group, per half
                    const int row = RB + i * 32 + rr + 8 * rg + 4 * h;
                    ered[row * ESLOT + (wv & 3) * 8 + (l & 7)] = make_uint2(v1, v2);
                }
            }
        }
    }
    __syncthreads();
    if (t < BM) {
        const uint2* e = &ered[t * ESLOT];
        unsigned v1 = 0xFFFFFFFFu, v2 = 0xFFFFFFFFu, v3 = 0xFFFFFFFFu;
        #pragma unroll
        for (int k = 0; k < 32; ++k) {
            const uint2 E = e[k];
            ins3k(v1, v2, v3, E.x);
            ins3k(v1, v2, v3, E.y);
        }
        p3[(size_t)(r0 + t) * QBLKS + qb] = make_uint4(v1, v2, v3, 0xFFFFFFFFu);
    }
}

// ---------------- phase 2: fp32-emulated (numpy semantics) rescore + gather ----------------
__global__ __launch_bounds__(256) void k_rescore(
        const uint4* __restrict__ p3,
        const float* __restrict__ x,
        const float* __restrict__ wt,
        const float* __restrict__ wsqf,
        const float* __restrict__ xsqf,
        float* __restrict__ outq,
        float* __restrict__ outi) {
    const int wv = threadIdx.x >> 6, l = threadIdx.x & 63;
    const int row = blockIdx.x * 4 + wv;

    const uint4 P = p3[(size_t)row * QBLKS + l];
    unsigned vk[3] = { P.x, P.y, P.z };

    unsigned gk = vk[0];
    #pragma unroll
    for (int m = 1; m < 64; m <<= 1) gk = min(gk, (unsigned)__shfl_xor((int)gk, m, 64));
    // threshold in key space: decode floored gm, add DELTA, re-encode, idx bits = 1s
    const float tf = dec_key(gk) + DELTA;
    const unsigned tb = __float_as_uint(tf);
    const unsigned tm = (unsigned)(((int)tb) >> 31) | 0x80000000u;
    const unsigned thrkey = (tb ^ tm) | 0x1FFFu;

    const float4* xp = (const float4*)(x + (size_t)row * ED + l * 8);
    const float4 xa = xp[0], xbv = xp[1];
    const float xsq = xsqf[row];

    float bestv = 3.4e38f; int bestq = 0x7fffffff;
    #pragma unroll
    for (int k = 0; k < 3; ++k) {
        unsigned long long mm = __ballot(vk[k] <= thrkey);
        while (mm) {
            const int ln = __ffsll(mm) - 1;
            mm &= mm - 1;
            const int q = __shfl((int)vk[k], ln, 64) & 0x1FFF;
            const float4* wp = (const float4*)(wt + (size_t)q * ED + l * 8);
            const float4 wa = wp[0], wbv = wp[1];
            double d = (double)xa.x * wa.x + (double)xa.y * wa.y
                     + (double)xa.z * wa.z + (double)xa.w * wa.w
                     + (double)xbv.x * wbv.x + (double)xbv.y * wbv.y
                     + (double)xbv.z * wbv.z + (double)xbv.w * wbv.w;
            #pragma unroll
            for (int m = 1; m < 64; m <<= 1) d += __shfl_xor(d, m, 64);
            // numpy fp32 semantics: fl32( fl32(x_sq - 2*dot) + w_sq ), first-occurrence argmin
            const float dotf = (float)d;
            const float t1 = __fadd_rn(xsq, __fmul_rn(-2.0f, dotf));
            const float sc = __fadd_rn(t1, wsqf[q]);
            if (sc < bestv || (sc == bestv && q < bestq)) { bestv = sc; bestq = q; }
        }
    }
    const float4* wp = (const float4*)(wt + (size_t)bestq * ED + l * 8);
    float4* op = (float4*)(outq + (size_t)row * ED + l * 8);
    op[0] = wp[0]; op[1] = wp[1];
    if (l == 0) outi[row] = (float)bestq;
}

extern "C" void kernel_launch(void* const* d_in, const int* in_sizes, int n_in,
                              void* d_out, int out_size, void* d_ws, size_t ws_size,
                              hipStream_t stream) {
    (void)in_sizes; (void)n_in; (void)out_size; (void)ws_size;
    const float* x  = (const float*)d_in[0];
    const float* wt = (const float*)d_in[1];

    char* ws = (char*)d_ws;
    unsigned long long* xb8 = (unsigned long long*)ws;               //  8,388,608 B
    unsigned long long* wb8 = (unsigned long long*)(ws + 8388608);   //  4,194,304 B
    float* wsqf = (float*)(ws + 12582912);                           //     32,768 B
    float* xsqf = (float*)(ws + 12615680);                           //     65,536 B
    uint4* p3   = (uint4*)(ws + 12681216);                           // 16,777,216 B (end ~29.5 MB)

    float* outq = (float*)d_out;
    float* outi = outq + (size_t)NROWS * ED;

    k_prep_sumsq<<<NROWS / SROWS, 256, 0, stream>>>(x,  xsqf, xb8, 1.0f);
    k_prep_sumsq<<<QNUM  / SROWS, 256, 0, stream>>>(wt, wsqf, wb8, 512.0f);  // 2^9 lifts w out of e4m3 subnormals
    k_gemm_top2<<<8192, 512, 0, stream>>>((const uint4*)xb8, (const uint4*)wb8, wsqf, p3);
    k_rescore<<<4096, 256, 0, stream>>>(p3, x, wt, wsqf, xsqf, outq, outi);
}

// Round 7
// 289.370 us; speedup vs baseline: 1.3259x; 1.2126x over previous
//
#include <hip/hip_runtime.h>
#include <stdint.h>

#define NROWS 16384
#define QNUM  8192
#define ED    512
#define BM    128
#define BN    128
#define KTILES 8           // K tiles of 64 elements
#define QBLKS  (QNUM / BN) // 64
#define DELTA  0.02f       // >=6 sigma of (err_i - err_j) for fp8 ranking noise
#define ESLOT  17          // 16 top2-key entries per row + 1 pad (uint2 units)

typedef int   i32x8  __attribute__((ext_vector_type(8)));   // 32 B fp8 fragment (8 VGPR)
typedef float f32x16 __attribute__((ext_vector_type(16)));  // 32x32 MFMA accumulator

// sortable key: monotone float->uint, low 13 bits replaced by q index (0..8191).
static __device__ __forceinline__ unsigned enc_key(float s, unsigned idx) {
    const unsigned b = __float_as_uint(s);
    const unsigned m = (unsigned)(((int)b) >> 31) | 0x80000000u;
    return ((b ^ m) & 0xFFFFE000u) | idx;
}
static __device__ __forceinline__ float dec_key(unsigned k) {
    const unsigned u = k & 0xFFFFE000u;
    return (u & 0x80000000u) ? __uint_as_float(u ^ 0x80000000u)
                             : __uint_as_float(~u);
}

static __device__ __forceinline__ void ins3k(unsigned& v1, unsigned& v2, unsigned& v3,
                                             unsigned k) {
    const bool b1 = k < v1, b2 = k < v2, b3 = k < v3;
    v3 = b2 ? v2 : (b3 ? k : v3);
    v2 = b1 ? v1 : (b2 ? k : v2);
    v1 = b1 ? k : v1;
}

// ---------------- fused prep: numpy-pairwise sumsq + fp32->fp8 MX-granule layout ----------------
// (verbatim from verified R2/R4 runs)
#define SROWS 32
#define SSTRIDE 520
__global__ __launch_bounds__(256) void k_prep_sumsq(const float* __restrict__ src,
                                                    float* __restrict__ dst_sq,
                                                    unsigned long long* __restrict__ dst8,
                                                    float scale) {
    __shared__ float ld[SROWS * SSTRIDE];
    const int t = threadIdx.x;
    const size_t base = (size_t)blockIdx.x * SROWS * ED;
    #pragma unroll
    for (int k = 0; k < 16; ++k) {
        int u = k * 256 + t;
        int row = u >> 7;
        int c4  = u & 127;
        float4 v = ((const float4*)(src + base))[u];
        float* d = ld + row * SSTRIDE + c4 * 4;
        d[0] = v.x; d[1] = v.y; d[2] = v.z; d[3] = v.w;
    }
    __syncthreads();
    const int row = t >> 3, j = t & 7;
    const float* a = ld + row * SSTRIDE;
    float B[4];
    #pragma unroll
    for (int b = 0; b < 4; ++b) {
        const float* p = a + b * 128 + j;
        float r = __fmul_rn(p[0], p[0]);
        #pragma unroll
        for (int i = 1; i < 16; ++i) {
            float q = p[8 * i];
            r = __fadd_rn(r, __fmul_rn(q, q));
        }
        float t1 = __fadd_rn(r,  __shfl_xor(r,  1, 64));
        float t2 = __fadd_rn(t1, __shfl_xor(t1, 2, 64));
        B[b]     = __fadd_rn(t2, __shfl_xor(t2, 4, 64));
    }
    if (j == 0)
        dst_sq[(size_t)blockIdx.x * SROWS + row] =
            __fadd_rn(__fadd_rn(B[0], B[1]), __fadd_rn(B[2], B[3]));

    // fp8 phase: thread (row, j) owns k-tile kt = j (64 elems = two 32 B blocks)
    #pragma unroll
    for (int kb = 0; kb < 2; ++kb) {
        const float* e = a + j * 64 + kb * 32;
        unsigned d[8];
        #pragma unroll
        for (int p = 0; p < 8; ++p) {
            int w0 = __builtin_amdgcn_cvt_pk_fp8_f32(e[4*p+0] * scale, e[4*p+1] * scale, 0,  false);
            w0     = __builtin_amdgcn_cvt_pk_fp8_f32(e[4*p+2] * scale, e[4*p+3] * scale, w0, true);
            d[p] = (unsigned)w0;
        }
        const size_t G = ((size_t)(blockIdx.x * 8 + j) * 64 + kb * 32 + row);
        uint4* dp = (uint4*)dst8 + G * 2;
        dp[0] = make_uint4(d[0], d[1], d[2], d[3]);
        dp[1] = make_uint4(d[4], d[5], d[6], d[7]);
    }
}

// ---------------- phase 1: MX fp8 MFMA + LDS staging (m97 pattern) + top-2 epilogue ----------------
// R7: fragments come from LDS, staged once per block per kt via global_load_lds.
// Why: the 6-round ledger shows the controlling variable is register footprint vs
// the 128-reg occupancy step (R1: 128 total -> 3.2 waves/SIMD, 90% issue; all MX
// reg-file variants: 160-192 total -> 2 waves/SIMD, <52%). LDS staging removes the
// prefetch buffers from the reg file (acc 64 + frag 32 + addr ~30 = ~126-140) and
// halves L2 traffic (each 2KB tile fetched once per block, not once per wave).
// Layout: MX granules are lane-linear in global, so global_load_lds (dest =
// base + lane*16) lands lane l's 32 B as halves at [l*16] and [1024+l*16];
// ds_read_b128 at l*16 is the fully-sequential conflict-free LDS pattern.
// Sync: m97 2-phase loop — stage(kt+1 -> buf^1), ds_read+MFMA on buf, barrier
// (compiler emits vmcnt(0) before s_barrier, draining the staging loads).
// C/D layout (HW-verified): col = lane&31, row = (reg&3)+8*(reg>>2)+4*(lane>>5).
__global__ __launch_bounds__(256, 2) void k_gemm_top2(
        const uint4* __restrict__ xb,   // MX-granule fp8 (32 B per lane-block)
        const uint4* __restrict__ wb,   // MX-granule fp8 (x512)
        const float* __restrict__ wsqf,
        uint4* __restrict__ p3) {
    // 2 bufs x 8 tiles x 2048 B = 32 KB; ered (17408 B) aliased on top (used after K-loop)
    __shared__ __align__(16) unsigned char smraw[2 * 8 * 2048];

    const int t  = threadIdx.x;
    const int wv = t >> 6;
    const int l  = t & 63;
    const int h  = l >> 5;   // lane half -> row +4
    const int cn = l & 31;   // MFMA col within 32-col tile
    const int RB = (wv >> 1) * 64;
    const int CB = (wv & 1) * 64;

    // XCD-aware swizzle: id%8 = XCD; each XCD keeps 8 q-panels L2-hot.
    const int id = blockIdx.x;
    const int qb = (id & 7) * 8 + ((id >> 3) & 7);  // 0..63
    const int rb = id >> 6;                          // 0..127
    const int q0 = qb * BN;
    const int r0 = rb * BM;

    f32x16 acc[2][2];
    #pragma unroll
    for (int i = 0; i < 2; ++i)
        #pragma unroll
        for (int j = 0; j < 2; ++j)
            #pragma unroll
            for (int r = 0; r < 16; ++r)
                acc[i][j][r] = 0.f;

    // staging: wave wv stages tiles {wv*2, wv*2+1}; tiles 0-3 = A row-tiles, 4-7 = B col-tiles
    const int T0 = wv * 2;
    const int pt0 = (T0 < 4) ? ((r0 >> 5) + T0)     : ((q0 >> 5) + T0 - 4);
    const int pt1 = (T0 < 4) ? ((r0 >> 5) + T0 + 1) : ((q0 >> 5) + T0 - 3);
    const char* srcb = (T0 < 4) ? (const char*)xb : (const char*)wb;
    const char* sb0 = srcb + ((size_t)(pt0 * 8) * 64 + l) * 32;
    const char* sb1 = srcb + ((size_t)(pt1 * 8) * 64 + l) * 32;

#define GLDS(gsrc, ldst) \
    __builtin_amdgcn_global_load_lds((const __attribute__((address_space(1))) unsigned*)(gsrc), \
                                     (__attribute__((address_space(3))) unsigned*)(ldst), 16, 0, 0)

#define STAGE(kt, buf) do {                                                \
        const char* s0_ = sb0 + (size_t)(kt) * 2048;                       \
        const char* s1_ = sb1 + (size_t)(kt) * 2048;                       \
        unsigned char* d0_ = &smraw[(buf) * 16384 + T0 * 2048];            \
        GLDS(s0_,      d0_);                                               \
        GLDS(s0_ + 16, d0_ + 1024);                                        \
        GLDS(s1_,      d0_ + 2048);                                        \
        GLDS(s1_ + 16, d0_ + 3072);                                        \
    } while (0)

    // read tiles for this wave: A tiles a0,a0+1 ; B tiles b0,b0+1
    const int a0 = (wv >> 1) * 2;
    const int b0 = 4 + (wv & 1) * 2;

#define DSR(dst, tile, buf) do {                                                        \
        const uint4 u0_ = *(const uint4*)&smraw[(buf) * 16384 + (tile) * 2048 + l * 16];\
        const uint4 u1_ = *(const uint4*)&smraw[(buf) * 16384 + (tile) * 2048 + 1024 + l * 16];\
        dst = (i32x8){(int)u0_.x, (int)u0_.y, (int)u0_.z, (int)u0_.w,                   \
                      (int)u1_.x, (int)u1_.y, (int)u1_.z, (int)u1_.w};                  \
    } while (0)

    STAGE(0, 0);
    __syncthreads();   // vmcnt(0) drained before barrier -> buf0 ready

    #pragma unroll
    for (int kt = 0; kt < KTILES; ++kt) {
        const int buf = kt & 1;
        if (kt + 1 < KTILES) STAGE(kt + 1, buf ^ 1);   // async: drains at end barrier
        i32x8 Af[2], Bf[2];
        DSR(Af[0], a0,     buf);
        DSR(Af[1], a0 + 1, buf);
        DSR(Bf[0], b0,     buf);
        DSR(Bf[1], b0 + 1, buf);
        __builtin_amdgcn_s_setprio(1);
        #pragma unroll
        for (int i = 0; i < 2; ++i)
            #pragma unroll
            for (int j = 0; j < 2; ++j)
                acc[i][j] = __builtin_amdgcn_mfma_scale_f32_32x32x64_f8f6f4(
                        Af[i], Bf[j], acc[i][j],
                        0, 0,                       // cbsz = fp8, blgp = fp8
                        0, 0x7F7F7F7F,              // scale A: e8m0 1.0
                        0, 0x7F7F7F7F);             // scale B: e8m0 1.0
        __builtin_amdgcn_s_setprio(0);
        __syncthreads();
    }

    // ---- epilogue (verbatim from verified R2): score = wsq - 2*dot*2^-9 ----
    uint2* ered = (uint2*)smraw;   // K-loop buffers dead; barrier above separates

    float wsqv[2]; unsigned kidx[2];
    #pragma unroll
    for (int j = 0; j < 2; ++j) {
        const int qj = q0 + CB + j * 32 + cn;
        wsqv[j] = wsqf[qj];
        kidx[j] = (unsigned)qj;
    }

    #pragma unroll
    for (int i = 0; i < 2; ++i) {
        #pragma unroll
        for (int rg = 0; rg < 4; ++rg) {
            #pragma unroll
            for (int rr = 0; rr < 4; ++rr) {
                const int reg = rg * 4 + rr;
                const unsigned k0 = enc_key(fmaf(-0.00390625f, acc[i][0][reg], wsqv[0]), kidx[0]);
                const unsigned k1 = enc_key(fmaf(-0.00390625f, acc[i][1][reg], wsqv[1]), kidx[1]);
                unsigned v1 = min(k0, k1);
                unsigned v2 = max(k0, k1);
                {
                    const unsigned o1 = __shfl_xor((int)v1, 8, 64);
                    const unsigned o2 = __shfl_xor((int)v2, 8, 64);
                    const unsigned nv1 = min(v1, o1);
                    v2 = min(max(v1, o1), min(v2, o2));
                    v1 = nv1;
                }
                {
                    const unsigned o1 = __shfl_xor((int)v1, 16, 64);
                    const unsigned o2 = __shfl_xor((int)v2, 16, 64);
                    const unsigned nv1 = min(v1, o1);
                    v2 = min(max(v1, o1), min(v2, o2));
                    v1 = nv1;
                }
                if ((l & 24) == 0) {
                    const int row = RB + i * 32 + rr + 8 * rg + 4 * h;
                    ered[row * ESLOT + (wv & 1) * 8 + (l & 7)] = make_uint2(v1, v2);
                }
            }
        }
    }
    __syncthreads();
    if (t < BM) {
        const uint2* e = &ered[t * ESLOT];
        unsigned v1 = 0xFFFFFFFFu, v2 = 0xFFFFFFFFu, v3 = 0xFFFFFFFFu;
        #pragma unroll
        for (int k = 0; k < 16; ++k) {
            const uint2 E = e[k];
            ins3k(v1, v2, v3, E.x);
            ins3k(v1, v2, v3, E.y);
        }
        p3[(size_t)(r0 + t) * QBLKS + qb] = make_uint4(v1, v2, v3, 0xFFFFFFFFu);
    }
}

// ---------------- phase 2: fp32-emulated (numpy semantics) rescore + gather ----------------
__global__ __launch_bounds__(256) void k_rescore(
        const uint4* __restrict__ p3,
        const float* __restrict__ x,
        const float* __restrict__ wt,
        const float* __restrict__ wsqf,
        const float* __restrict__ xsqf,
        float* __restrict__ outq,
        float* __restrict__ outi) {
    const int wv = threadIdx.x >> 6, l = threadIdx.x & 63;
    const int row = blockIdx.x * 4 + wv;

    const uint4 P = p3[(size_t)row * QBLKS + l];
    unsigned vk[3] = { P.x, P.y, P.z };

    unsigned gk = vk[0];
    #pragma unroll
    for (int m = 1; m < 64; m <<= 1) gk = min(gk, (unsigned)__shfl_xor((int)gk, m, 64));
    const float tf = dec_key(gk) + DELTA;
    const unsigned tb = __float_as_uint(tf);
    const unsigned tm = (unsigned)(((int)tb) >> 31) | 0x80000000u;
    const unsigned thrkey = (tb ^ tm) | 0x1FFFu;

    const float4* xp = (const float4*)(x + (size_t)row * ED + l * 8);
    const float4 xa = xp[0], xbv = xp[1];
    const float xsq = xsqf[row];

    float bestv = 3.4e38f; int bestq = 0x7fffffff;
    #pragma unroll
    for (int k = 0; k < 3; ++k) {
        unsigned long long mm = __ballot(vk[k] <= thrkey);
        while (mm) {
            const int ln = __ffsll(mm) - 1;
            mm &= mm - 1;
            const int q = __shfl((int)vk[k], ln, 64) & 0x1FFF;
            const float4* wp = (const float4*)(wt + (size_t)q * ED + l * 8);
            const float4 wa = wp[0], wbv = wp[1];
            double d = (double)xa.x * wa.x + (double)xa.y * wa.y
                     + (double)xa.z * wa.z + (double)xa.w * wa.w
                     + (double)xbv.x * wbv.x + (double)xbv.y * wbv.y
                     + (double)xbv.z * wbv.z + (double)xbv.w * wbv.w;
            #pragma unroll
            for (int m = 1; m < 64; m <<= 1) d += __shfl_xor(d, m, 64);
            const float dotf = (float)d;
            const float t1 = __fadd_rn(xsq, __fmul_rn(-2.0f, dotf));
            const float sc = __fadd_rn(t1, wsqf[q]);
            if (sc < bestv || (sc == bestv && q < bestq)) { bestv = sc; bestq = q; }
        }
    }
    const float4* wp = (const float4*)(wt + (size_t)bestq * ED + l * 8);
    float4* op = (float4*)(outq + (size_t)row * ED + l * 8);
    op[0] = wp[0]; op[1] = wp[1];
    if (l == 0) outi[row] = (float)bestq;
}

extern "C" void kernel_launch(void* const* d_in, const int* in_sizes, int n_in,
                              void* d_out, int out_size, void* d_ws, size_t ws_size,
                              hipStream_t stream) {
    (void)in_sizes; (void)n_in; (void)out_size; (void)ws_size;
    const float* x  = (const float*)d_in[0];
    const float* wt = (const float*)d_in[1];

    char* ws = (char*)d_ws;
    unsigned long long* xb8 = (unsigned long long*)ws;               //  8,388,608 B
    unsigned long long* wb8 = (unsigned long long*)(ws + 8388608);   //  4,194,304 B
    float* wsqf = (float*)(ws + 12582912);                           //     32,768 B
    float* xsqf = (float*)(ws + 12615680);                           //     65,536 B
    uint4* p3   = (uint4*)(ws + 12681216);                           // 16,777,216 B (end ~29.5 MB)

    float* outq = (float*)d_out;
    float* outi = outq + (size_t)NROWS * ED;

    k_prep_sumsq<<<NROWS / SROWS, 256, 0, stream>>>(x,  xsqf, xb8, 1.0f);
    k_prep_sumsq<<<QNUM  / SROWS, 256, 0, stream>>>(wt, wsqf, wb8, 512.0f);  // 2^9 lifts w out of e4m3 subnormals
    k_gemm_top2<<<8192, 256, 0, stream>>>((const uint4*)xb8, (const uint4*)wb8, wsqf, p3);
    k_rescore<<<4096, 256, 0, stream>>>(p3, x, wt, wsqf, xsqf, outq, outi);
}

// Round 11
// 238.876 us; speedup vs baseline: 1.6062x; 1.2114x over previous
//
#include <hip/hip_runtime.h>
#include <stdint.h>

#define NROWS 16384
#define QNUM  8192
#define ED    512
#define BM    128
#define BN    128
#define KTILES 8           // K tiles of 64 elements
#define QBLKS  (QNUM / BN) // 64
#define DELTA  0.02f       // >=6 sigma of (err_i - err_j) for fp8 ranking noise
#define ESLOT  17          // 16 top2-key entries per row + 1 pad (uint2 units)

typedef long  l2    __attribute__((ext_vector_type(2)));   // 16 B = two i64 fp8x8 fragments
typedef float f32x4 __attribute__((ext_vector_type(4)));

// sortable key: monotone float->uint, low 13 bits replaced by q index (0..8191).
// score perturbation from clearing 13 mantissa bits <= ~6e-5 at |s|~0.1 — absorbed
// by DELTA. min-key == (min score, tie -> min idx).
static __device__ __forceinline__ unsigned enc_key(float s, unsigned idx) {
    const unsigned b = __float_as_uint(s);
    const unsigned m = (unsigned)(((int)b) >> 31) | 0x80000000u;
    return ((b ^ m) & 0xFFFFE000u) | idx;
}
// decode key -> floored float value (<= true score)
static __device__ __forceinline__ float dec_key(unsigned k) {
    const unsigned u = k & 0xFFFFE000u;
    return (u & 0x80000000u) ? __uint_as_float(u ^ 0x80000000u)
                             : __uint_as_float(~u);
}

static __device__ __forceinline__ void ins3k(unsigned& v1, unsigned& v2, unsigned& v3,
                                             unsigned k) {
    const bool b1 = k < v1, b2 = k < v2, b3 = k < v3;
    v3 = b2 ? v2 : (b3 ? k : v3);
    v2 = b1 ? v1 : (b2 ? k : v2);
    v1 = b1 ? k : v1;
}

// ---------------- fused prep: numpy-pairwise sumsq + fp32->fp8 fragment-tiled ----------------
// R8: body is the R1-verified kernel verbatim (numpy-pairwise sumsq tree + R9
// fragment-tiled granule layout); the two launches (x, w) are fused into ONE
// dispatch with a block-uniform path select — saves a launch slot + tail.
#define SROWS 32
#define SSTRIDE 520
static __device__ __forceinline__ void prep_body(const float* __restrict__ src,
                                                 float* __restrict__ dst_sq,
                                                 unsigned long long* __restrict__ dst8,
                                                 float scale, int blk) {
    __shared__ float ld[SROWS * SSTRIDE];
    const int t = threadIdx.x;
    const size_t base = (size_t)blk * SROWS * ED;
    #pragma unroll
    for (int k = 0; k < 16; ++k) {
        int u = k * 256 + t;
        int row = u >> 7;
        int c4  = u & 127;
        float4 v = ((const float4*)(src + base))[u];
        float* d = ld + row * SSTRIDE + c4 * 4;
        d[0] = v.x; d[1] = v.y; d[2] = v.z; d[3] = v.w;
    }
    __syncthreads();
    const int row = t >> 3, j = t & 7;
    const float* a = ld + row * SSTRIDE;
    float B[4];
    #pragma unroll
    for (int b = 0; b < 4; ++b) {
        const float* p = a + b * 128 + j;
        float r = __fmul_rn(p[0], p[0]);
        #pragma unroll
        for (int i = 1; i < 16; ++i) {
            float q = p[8 * i];
            r = __fadd_rn(r, __fmul_rn(q, q));
        }
        float t1 = __fadd_rn(r,  __shfl_xor(r,  1, 64));
        float t2 = __fadd_rn(t1, __shfl_xor(t1, 2, 64));
        B[b]     = __fadd_rn(t2, __shfl_xor(t2, 4, 64));
    }
    if (j == 0)
        dst_sq[(size_t)blk * SROWS + row] =
            __fadd_rn(__fadd_rn(B[0], B[1]), __fadd_rn(B[2], B[3]));

    // fp8 phase: thread (row, j) converts granules kk = j*8 + gi (gi 0..7)
    const int gr = blk * SROWS + row;               // global row
    const int rt = gr >> 4, cc = gr & 15;
    #pragma unroll
    for (int gi = 0; gi < 8; ++gi) {
        const float* e = a + (j * 8 + gi) * 8;      // 8 consecutive elems
        int lo = __builtin_amdgcn_cvt_pk_fp8_f32(e[0] * scale, e[1] * scale, 0, false);
        lo     = __builtin_amdgcn_cvt_pk_fp8_f32(e[2] * scale, e[3] * scale, lo, true);
        int hi = __builtin_amdgcn_cvt_pk_fp8_f32(e[4] * scale, e[5] * scale, 0, false);
        hi     = __builtin_amdgcn_cvt_pk_fp8_f32(e[6] * scale, e[7] * scale, hi, true);
        const unsigned long long v = (unsigned)lo | ((unsigned long long)(unsigned)hi << 32);
        const int g = gi & 3, half = gi >> 2;       // kt = j
        dst8[((size_t)(rt * 8 + j) * 64 + g * 16 + cc) * 2 + half] = v;
    }
}

__global__ __launch_bounds__(256) void k_prep_fused(const float* __restrict__ x,
                                                    const float* __restrict__ wt,
                                                    float* __restrict__ xsqf,
                                                    float* __restrict__ wsqf,
                                                    unsigned long long* __restrict__ xb8,
                                                    unsigned long long* __restrict__ wb8) {
    const int b = blockIdx.x;
    const bool isw = (b >= NROWS / SROWS);           // block-uniform
    if (isw) prep_body(wt, wsqf, wb8, 512.0f, b - NROWS / SROWS);  // 2^9 lifts w out of e4m3 subnormals
    else     prep_body(x,  xsqf, xb8, 1.0f,   b);
}

// ---------------- phase 1: fp8 MFMA + sortable-key top-2 epilogue ----------------
// R1-verified kernel, verbatim (119.5 us, MfmaUtil 48.8%, VALUBusy 41%, 90% issue
// util at 64 VGPR + 64 AGPR = 128 total -> 3.2 waves/SIMD). Six MX-rate variants
// (R2-R7) all lost: the 8-VGPR MX operands push every config over the 128-reg
// occupancy step or into serialization/spill; overlap density beats MFMA rate here.
__global__ __launch_bounds__(256, 2) void k_gemm_top2(
        const l2* __restrict__ xb,    // fragment-tiled fp8
        const l2* __restrict__ wb,    // fragment-tiled fp8 (x512)
        const float* __restrict__ wsqf,
        uint4* __restrict__ p3) {
    __shared__ uint2 ered[BM * ESLOT];   // 17,408 B

    const int t  = threadIdx.x;
    const int wv = t >> 6;
    const int l  = t & 63;
    const int c  = l & 15;   // MFMA col / A-row lane
    const int g  = l >> 4;   // MFMA quad
    const int RB = (wv >> 1) * 64;
    const int CB = (wv & 1) * 64;

    // XCD-aware swizzle: id%8 = XCD; each XCD keeps 8 q-panels L2-hot.
    const int id = blockIdx.x;
    const int qb = (id & 7) * 8 + ((id >> 3) & 7);  // 0..63
    const int rb = id >> 6;                          // 0..127
    const int q0 = qb * BN;
    const int r0 = rb * BM;

    f32x4 acc[4][4];
    #pragma unroll
    for (int i = 0; i < 4; ++i)
        #pragma unroll
        for (int j = 0; j < 4; ++j)
            acc[i][j] = (f32x4){0.f, 0.f, 0.f, 0.f};

    const l2* ga = xb + ((size_t)((r0 + RB) >> 4) * 8) * 64 + l;
    const l2* gb = wb + ((size_t)((q0 + CB) >> 4) * 8) * 64 + l;

    l2 Af[2][4], Bf[2][4];   // [buf][tile]

    #pragma unroll
    for (int i = 0; i < 4; ++i) Af[0][i] = ga[(size_t)(i * 8) * 64];
    #pragma unroll
    for (int j = 0; j < 4; ++j) Bf[0][j] = gb[(size_t)(j * 8) * 64];

    #pragma unroll
    for (int kt = 0; kt < KTILES; ++kt) {
        const int cur = kt & 1, nxt = cur ^ 1;
        if (kt + 1 < KTILES) {   // depth-1 prefetch: next tile in flight across MFMAs
            #pragma unroll
            for (int i = 0; i < 4; ++i) Af[nxt][i] = ga[(size_t)(i * 8 + kt + 1) * 64];
            #pragma unroll
            for (int j = 0; j < 4; ++j) Bf[nxt][j] = gb[(size_t)(j * 8 + kt + 1) * 64];
        }
        #pragma unroll
        for (int s = 0; s < 2; ++s)
            #pragma unroll
            for (int i = 0; i < 4; ++i)
                #pragma unroll
                for (int j = 0; j < 4; ++j) {
                    const long a8 = s ? Af[cur][i].y : Af[cur][i].x;
                    const long b8 = s ? Bf[cur][j].y : Bf[cur][j].x;
                    acc[i][j] = __builtin_amdgcn_mfma_f32_16x16x32_fp8_fp8(a8, b8, acc[i][j], 0, 0, 0);
                }
    }

    // epilogue: score = wsq - 2*dot*2^-9 (w scaled by 2^9 at prep)
    float wsqv[4]; unsigned kidx[4];
    #pragma unroll
    for (int j = 0; j < 4; ++j) {
        const int qj = q0 + CB + j * 16 + c;
        wsqv[j] = wsqf[qj];
        kidx[j] = (unsigned)qj;
    }

    #pragma unroll
    for (int i = 0; i < 4; ++i) {
        #pragma unroll
        for (int r = 0; r < 4; ++r) {
            unsigned k0 = enc_key(fmaf(-0.00390625f, acc[i][0][r], wsqv[0]), kidx[0]);
            unsigned k1 = enc_key(fmaf(-0.00390625f, acc[i][1][r], wsqv[1]), kidx[1]);
            unsigned k2 = enc_key(fmaf(-0.00390625f, acc[i][2][r], wsqv[2]), kidx[2]);
            unsigned k3 = enc_key(fmaf(-0.00390625f, acc[i][3][r], wsqv[3]), kidx[3]);
            // top-2 of 4 (keys are distinct: idx embedded)
            const unsigned a01 = min(k0, k1), b01 = max(k0, k1);
            const unsigned a23 = min(k2, k3), b23 = max(k2, k3);
            unsigned v1 = min(a01, a23);
            unsigned v2 = min(min(max(a01, a23), b01), b23);
            // single xor-8 merge of two disjoint 8-col groups
            const unsigned o1 = __shfl_xor((int)v1, 8, 64);
            const unsigned o2 = __shfl_xor((int)v2, 8, 64);
            const unsigned nv1 = min(v1, o1);
            v2 = min(min(max(v1, o1), v2), o2);
            v1 = nv1;
            if (c < 8) {
                const int row = RB + i * 16 + g * 4 + r;
                ered[row * ESLOT + (wv & 1) * 8 + c] = make_uint2(v1, v2);
            }
        }
    }
    __syncthreads();
    if (t < BM) {
        const uint2* e = &ered[t * ESLOT];
        unsigned v1 = 0xFFFFFFFFu, v2 = 0xFFFFFFFFu, v3 = 0xFFFFFFFFu;
        #pragma unroll
        for (int k = 0; k < 16; ++k) {
            const uint2 E = e[k];
            ins3k(v1, v2, v3, E.x);
            ins3k(v1, v2, v3, E.y);
        }
        p3[(size_t)(r0 + t) * QBLKS + qb] = make_uint4(v1, v2, v3, 0xFFFFFFFFu);
    }
}

// ---------------- phase 2: fp32-emulated (numpy semantics) rescore + gather ----------------
__global__ __launch_bounds__(256) void k_rescore(
        const uint4* __restrict__ p3,
        const float* __restrict__ x,
        const float* __restrict__ wt,
        const float* __restrict__ wsqf,
        const float* __restrict__ xsqf,
        float* __restrict__ outq,
        float* __restrict__ outi) {
    const int wv = threadIdx.x >> 6, l = threadIdx.x & 63;
    const int row = blockIdx.x * 4 + wv;

    const uint4 P = p3[(size_t)row * QBLKS + l];
    unsigned vk[3] = { P.x, P.y, P.z };

    unsigned gk = vk[0];
    #pragma unroll
    for (int m = 1; m < 64; m <<= 1) gk = min(gk, (unsigned)__shfl_xor((int)gk, m, 64));
    // threshold in key space: decode floored gm, add DELTA, re-encode, idx bits = 1s
    const float tf = dec_key(gk) + DELTA;
    const unsigned tb = __float_as_uint(tf);
    const unsigned tm = (unsigned)(((int)tb) >> 31) | 0x80000000u;
    const unsigned thrkey = (tb ^ tm) | 0x1FFFu;

    const float4* xp = (const float4*)(x + (size_t)row * ED + l * 8);
    const float4 xa = xp[0], xbv = xp[1];
    const float xsq = xsqf[row];

    float bestv = 3.4e38f; int bestq = 0x7fffffff;
    #pragma unroll
    for (int k = 0; k < 3; ++k) {
        unsigned long long mm = __ballot(vk[k] <= thrkey);
        while (mm) {
            const int ln = __ffsll(mm) - 1;
            mm &= mm - 1;
            const int q = __shfl((int)vk[k], ln, 64) & 0x1FFF;
            const float4* wp = (const float4*)(wt + (size_t)q * ED + l * 8);
            const float4 wa = wp[0], wbv = wp[1];
            double d = (double)xa.x * wa.x + (double)xa.y * wa.y
                     + (double)xa.z * wa.z + (double)xa.w * wa.w
                     + (double)xbv.x * wbv.x + (double)xbv.y * wbv.y
                     + (double)xbv.z * wbv.z + (double)xbv.w * wbv.w;
            #pragma unroll
            for (int m = 1; m < 64; m <<= 1) d += __shfl_xor(d, m, 64);
            // numpy fp32 semantics: fl32( fl32(x_sq - 2*dot) + w_sq ), first-occurrence argmin
            const float dotf = (float)d;
            const float t1 = __fadd_rn(xsq, __fmul_rn(-2.0f, dotf));
            const float sc = __fadd_rn(t1, wsqf[q]);
            if (sc < bestv || (sc == bestv && q < bestq)) { bestv = sc; bestq = q; }
        }
    }
    const float4* wp = (const float4*)(wt + (size_t)bestq * ED + l * 8);
    float4* op = (float4*)(outq + (size_t)row * ED + l * 8);
    op[0] = wp[0]; op[1] = wp[1];
    if (l == 0) outi[row] = (float)bestq;
}

extern "C" void kernel_launch(void* const* d_in, const int* in_sizes, int n_in,
                              void* d_out, int out_size, void* d_ws, size_t ws_size,
                              hipStream_t stream) {
    (void)in_sizes; (void)n_in; (void)out_size; (void)ws_size;
    const float* x  = (const float*)d_in[0];
    const float* wt = (const float*)d_in[1];

    char* ws = (char*)d_ws;
    unsigned long long* xb8 = (unsigned long long*)ws;               //  8,388,608 B
    unsigned long long* wb8 = (unsigned long long*)(ws + 8388608);   //  4,194,304 B
    float* wsqf = (float*)(ws + 12582912);                           //     32,768 B
    float* xsqf = (float*)(ws + 12615680);                           //     65,536 B
    uint4* p3   = (uint4*)(ws + 12681216);                           // 16,777,216 B (end ~29.5 MB)

    float* outq = (float*)d_out;
    float* outi = outq + (size_t)NROWS * ED;

    k_prep_fused<<<NROWS / SROWS + QNUM / SROWS, 256, 0, stream>>>(x, wt, xsqf, wsqf, xb8, wb8);
    k_gemm_top2<<<8192, 256, 0, stream>>>((const l2*)xb8, (const l2*)wb8, wsqf, p3);
    k_rescore<<<4096, 256, 0, stream>>>(p3, x, wt, wsqf, xsqf, outq, outi);
}